// Round 13
// baseline (179.713 us; speedup 1.0000x reference)
//
#include <hip/hip_runtime.h>
#include <hip/hip_bf16.h>

// LocalAggregation: B=8, N=2048, K=32, D=64, C1=64, C2=128, R=0.15, EPS=1e-5
// Factored stats1 (validated R7-R10):
//   h1[row,c] = g[m,c] + dx*wx[c]+dy*wy[c]+dz*wz[c],  g = feat @ W1[3:]
//   sum1[c]   = SUM_m cnt[m] g[m,c] + wx M1x + wy M1y + wz M1z
//   sumsq1[c] = SUM_m cnt g^2 + 2(wx A3x + wy A3y + wz A3z) + quadratic moments
// Session ledger (counters-verified):
//   R13/R14: multi-site kD unroll -> gather hoist -> scratch spill. Rolled
//     loop / single-site body prevents it.
//   R15/R16: same-address global atomics = #blocks x ~130cy chain -> partial
//     stores + narrow reduce kernels everywhere.
//   R17: cross-block fences = L2 writeback storm (non-coherent XCD L2s).
//   R18: fence-free fusion kQ=k1+kP (block-local), kR->kB (across boundary).
//   R19 (174us, BEST): kD v9 rolled 4-site @1024 blocks (W2 amortized).
//   R20: coop mega-kernel -> 64-VGPR cap -> spill (371us).
//   R21: in-kD kS fold with DEFAULT unroll -> compiler pipelined the 128-deep
//     fold -> VGPR 48->128, Occ 19% (203us). The idea wasn't wrong; the
//     unbounded unroll was.
//   R22: k45 folding FULL stats2P per block = 256MB L3 traffic (195us).
//     RULE: redundant-fold cost = nblocks x fold_bytes << one boundary.
//   R23: kQ @2 blocks/CU neutral (178us) — kQ is not occupancy-bound.
// R24: R19 verbatim EXCEPT kD absorbs kS with a BOUNDED fold:
//   #pragma unroll 8 on the 128-deep A_p column fold (8 in-flight loads,
//   ~+10 VGPR, ~1.5us L2-hot) + mr-style 2-stage momP fold. Saves the kS
//   launch + boundary (~12-15us). 6 -> 5 launches. Tripwire: kD VGPR > 80
//   or total >= 174 -> revert to R19 and declare the boundary floor.
// gamma2>0 => max-pool commutes with bn2+relu (k45).

#define BB 8
#define NN 2048
#define KK 32
#define DD 64
#define CC1 64
#define CC2 128
#define TOTROWS (BB*NN*KK) // 524288
#define SITES (BB*NN)      // 16384
#define PSLICES 256        // partial sets (kQ blocks)
#define DBLOCKS 1024       // kD blocks

typedef __bf16 bf16x8 __attribute__((ext_vector_type(8)));
typedef float  f32x4  __attribute__((ext_vector_type(4)));

__device__ __forceinline__ void lds_add(float* p, float v) {
  __hip_atomic_fetch_add(p, v, __ATOMIC_RELAXED, __HIP_MEMORY_SCOPE_WORKGROUP);
}

// ---------------- KQ: fused ball query + scatter (k1+kP, block-local dep) ----------------
// 256 blocks x 1024 thr; block = (batch, 64-site slice).  (R19 geometry.)
// Phase 1: stage P[2048] float4 (32 KB) + zero accumulators.
// Phase 2: ball query, 16 waves x 4 queries; idx -> global AND idxL (LDS).
// Phase 3: scatter from idxL, positions from LDS P. u32 2^22 fixed point:
//   per-block |sum dx| <= 2048 * 0.15 * 2^22 = 1.29e9 < 2^31.
// Phase 4: partial stores Pc/Px/Py/Pz + momP. ZERO global atomics, no fences.
__global__ __launch_bounds__(1024, 1) void kQ_ball_scatter(
    const float* __restrict__ pos, int* __restrict__ idx,
    float* __restrict__ Pc, float* __restrict__ Px,
    float* __restrict__ Py, float* __restrict__ Pz,
    float* __restrict__ momP)
{
  __shared__ float4 P[NN];                               // 32 KB
  __shared__ unsigned int Sc[NN], Sx[NN], Sy[NN], Sz[NN]; // 32 KB
  __shared__ int idxL[64*KK];                            // 8 KB
  __shared__ float mred[16*9];
  const int b = blockIdx.x >> 5;       // 32 slices per batch
  const int slice = blockIdx.x & 31;   // 64 sites each
  // phase 1: stage P (verbatim k1 arithmetic: no contraction) + zero acc
  for (int i = threadIdx.x; i < NN; i += 1024) {
    const float* p = pos + ((size_t)b*NN + i)*3;
    float x = p[0], y = p[1], z = p[2];
    float s = __fadd_rn(__fadd_rn(__fmul_rn(x,x), __fmul_rn(y,y)), __fmul_rn(z,z));
    P[i] = make_float4(x, y, z, s);
    Sc[i] = 0u; Sx[i] = 0u; Sy[i] = 0u; Sz[i] = 0u;
  }
  __syncthreads();
  // phase 2: ball query (16 waves, 4 site-local queries each)
  const int wave = threadIdx.x >> 6, lane = threadIdx.x & 63;
  const float R2 = (float)(0.15 * 0.15);
  const unsigned long long lt = (lane == 63) ? 0x7fffffffffffffffull
                                             : ((1ull << lane) - 1ull);
  for (int qi = wave; qi < 64; qi += 16) {
    const int q = slice*64 + qi;             // batch-local point id
    const float4 Q = P[q];
    int* ip = idx + ((size_t)b*NN + q)*KK;
    int* il = idxL + qi*KK;
    int cnt = 0, first = -1;
    for (int step = 0; step < 32; ++step) {
      float4 p = P[step*64 + lane];
      float d = __fmul_rn(Q.x, p.x);
      d = fmaf(Q.y, p.y, d);
      d = fmaf(Q.z, p.z, d);
      float sq = __fsub_rn(__fadd_rn(Q.w, p.w), __fmul_rn(2.0f, d));
      bool in = !(sq > R2);
      unsigned long long mask = __ballot(in);
      if (first < 0 && mask) first = step*64 + (int)__builtin_ctzll(mask);
      int dst = cnt + (int)__popcll(mask & lt);
      if (in && dst < KK) { ip[dst] = step*64 + lane; il[dst] = step*64 + lane; }
      cnt += (int)__popcll(mask);
      if (cnt >= KK) break;
    }
    if (lane >= cnt && lane < KK) { ip[lane] = first; il[lane] = first; }
  }
  __syncthreads();
  // phase 3: scatter (thread = (site sl, k-group kg of 2 k's))
  const int sl = threadIdx.x >> 4;     // site-local 0..63
  const int kg = threadIdx.x & 15;
  const int ip0 = idxL[sl*KK];
  const float4 C = P[slice*64 + sl];
  const float FS = 4194304.0f;         // 2^22
  float m1x=0.f,m1y=0.f,m1z=0.f,mxx=0.f,myy=0.f,mzz=0.f,mxy=0.f,mxz=0.f,myz=0.f;
  int wt = 0;
  #pragma unroll
  for (int j = 0; j < 2; ++j) {
    const int k = kg*2 + j;
    const int m = idxL[sl*KK + k];
    const float4 Pm = P[m];
    float dx = Pm.x - C.x;
    float dy = Pm.y - C.y;
    float dz = Pm.z - C.z;
    if (k > 0 && m == ip0) {
      ++wt;                             // padding: aggregate
    } else {
      atomicAdd(&Sc[m], 1u);            // ds_add_u32
      atomicAdd(&Sx[m], (unsigned int)__float2int_rn(dx*FS));
      atomicAdd(&Sy[m], (unsigned int)__float2int_rn(dy*FS));
      atomicAdd(&Sz[m], (unsigned int)__float2int_rn(dz*FS));
    }
    m1x += dx; m1y += dy; m1z += dz;    // moments include padding rows
    mxx = fmaf(dx,dx,mxx); myy = fmaf(dy,dy,myy); mzz = fmaf(dz,dz,mzz);
    mxy = fmaf(dx,dy,mxy); mxz = fmaf(dx,dz,mxz); myz = fmaf(dy,dz,myz);
  }
  if (wt > 0) {
    const float4 P0 = P[ip0];
    float dx0 = P0.x - C.x;
    float dy0 = P0.y - C.y;
    float dz0 = P0.z - C.z;
    atomicAdd(&Sc[ip0], (unsigned int)wt);
    atomicAdd(&Sx[ip0], (unsigned int)(wt*__float2int_rn(dx0*FS)));
    atomicAdd(&Sy[ip0], (unsigned int)(wt*__float2int_rn(dy0*FS)));
    atomicAdd(&Sz[ip0], (unsigned int)(wt*__float2int_rn(dz0*FS)));
  }
  // per-wave moment reduce -> LDS -> per-block partial store
  const int wv = threadIdx.x >> 6;     // 0..15
  float vals[9] = {m1x,m1y,m1z,mxx,myy,mzz,mxy,mxz,myz};
  #pragma unroll
  for (int i = 0; i < 9; ++i) {
    float v = vals[i];
    #pragma unroll
    for (int s = 1; s < 64; s <<= 1) v += __shfl_xor(v, s, 64);
    if (lane == 0) mred[wv*9 + i] = v;
  }
  __syncthreads();
  // phase 4: partial stores
  const float IS = 2.38418579101562500e-7f;  // 2^-22
  float* pc = Pc + (size_t)blockIdx.x*NN;
  float* px = Px + (size_t)blockIdx.x*NN;
  float* py = Py + (size_t)blockIdx.x*NN;
  float* pz = Pz + (size_t)blockIdx.x*NN;
  for (int i = threadIdx.x; i < NN; i += 1024) {
    pc[i] = (float)Sc[i];
    px[i] = (float)(int)Sx[i] * IS;
    py[i] = (float)(int)Sy[i] * IS;
    pz[i] = (float)(int)Sz[i] * IS;
  }
  if (threadIdx.x < 9) {
    float s = 0.f;
    #pragma unroll
    for (int w2 = 0; w2 < 16; ++w2) s += mred[w2*9 + threadIdx.x];
    momP[(size_t)blockIdx.x*16 + threadIdx.x] = s;
  }
}

// ---------------- KB v4: g = feat @ W1[3:] + A-sums; kR fused cooperatively ----------------
// 128 blocks x 256 thr -> 512 waves x 2 M-tiles; block covers 128 rows (one batch).
// Staging: cntL/dxL/dyL/dzL[128] = 32-partial sums for this block's rows
// (dep crosses the kQ->kB launch boundary; no fences).
// A layout: [0:64) Sum cnt*g, [64:128) Sum cnt*g^2, [128:192) Sum g*DX,
//           [192:256) Sum g*DY, [256:320) Sum g*DZ  -> A_p[blk][320].
__global__ __launch_bounds__(256) void kB_g(const float* __restrict__ feat,
                                            const float* __restrict__ W1,
                                            const float* __restrict__ Pc,
                                            const float* __restrict__ Px,
                                            const float* __restrict__ Py,
                                            const float* __restrict__ Pz,
                                            float* __restrict__ g,
                                            float* __restrict__ A_p)
{
  __shared__ float red[320];
  __shared__ float cntL[128], dxL[128], dyL[128], dzL[128];
  for (int i = threadIdx.x; i < 320; i += 256) red[i] = 0.f;
  const int row0B = blockIdx.x * 128;
  const int bb = row0B >> 11;          // batch of this block (128 | 2048)
  for (int r2 = threadIdx.x; r2 < 128; r2 += 256) {
    const int m = (row0B + r2) & (NN-1);
    float s0 = 0.f, s1 = 0.f, s2 = 0.f, s3 = 0.f;
    #pragma unroll 4
    for (int q = 0; q < 32; ++q) {
      const size_t base = (size_t)(bb*32 + q)*NN + m;
      s0 += Pc[base]; s1 += Px[base]; s2 += Py[base]; s3 += Pz[base];
    }
    cntL[r2] = s0; dxL[r2] = s1; dyL[r2] = s2; dzL[r2] = s3;
  }
  __syncthreads();
  const int lane = threadIdx.x & 63;
  const int quad = lane >> 4;
  const int col  = lane & 15;
  const int gw = (blockIdx.x*256 + threadIdx.x) >> 6;   // 0..511

  bf16x8 Bf[2][4];
  #pragma unroll
  for (int kt = 0; kt < 2; ++kt)
    #pragma unroll
    for (int nt = 0; nt < 4; ++nt) {
      bf16x8 v;
      #pragma unroll
      for (int j = 0; j < 8; ++j)
        v[j] = (__bf16)W1[(3 + kt*32 + quad*8 + j)*CC1 + nt*16 + col];
      Bf[kt][nt] = v;
    }
  float a1[4], a2[4], a3[4], a4[4], a5[4];
  #pragma unroll
  for (int nt = 0; nt < 4; ++nt) { a1[nt]=0.f; a2[nt]=0.f; a3[nt]=0.f; a4[nt]=0.f; a5[nt]=0.f; }

  for (int t = 0; t < 2; ++t) {
    const int row0 = (gw*2 + t) * 16;
    bf16x8 Af[2];
    #pragma unroll
    for (int kt = 0; kt < 2; ++kt) {
      const float4* fp =
        (const float4*)(feat + (size_t)(row0 + col)*DD + kt*32 + quad*8);
      float4 f0 = fp[0], f1 = fp[1];
      float fv[8] = {f0.x,f0.y,f0.z,f0.w,f1.x,f1.y,f1.z,f1.w};
      bf16x8 v;
      #pragma unroll
      for (int j = 0; j < 8; ++j) v[j] = (__bf16)fv[j];
      Af[kt] = v;
    }
    float cw[4], dxw[4], dyw[4], dzw[4];
    #pragma unroll
    for (int r = 0; r < 4; ++r) {
      int rl = row0 - row0B + quad*4 + r;   // 0..127 within block
      cw[r] = cntL[rl]; dxw[r] = dxL[rl]; dyw[r] = dyL[rl]; dzw[r] = dzL[rl];
    }
    #pragma unroll
    for (int nt = 0; nt < 4; ++nt) {
      f32x4 a = {0.f, 0.f, 0.f, 0.f};
      a = __builtin_amdgcn_mfma_f32_16x16x32_bf16(Af[0], Bf[0][nt], a, 0, 0, 0);
      a = __builtin_amdgcn_mfma_f32_16x16x32_bf16(Af[1], Bf[1][nt], a, 0, 0, 0);
      #pragma unroll
      for (int r = 0; r < 4; ++r) {
        float v = a[r];
        g[(size_t)(row0 + quad*4 + r)*CC1 + nt*16 + col] = v;
        float cv = cw[r]*v;
        a1[nt] += cv; a2[nt] = fmaf(cv, v, a2[nt]);
        a3[nt] = fmaf(dxw[r], v, a3[nt]);
        a4[nt] = fmaf(dyw[r], v, a4[nt]);
        a5[nt] = fmaf(dzw[r], v, a5[nt]);
      }
    }
  }
  #pragma unroll
  for (int nt = 0; nt < 4; ++nt) {
    float v1=a1[nt], v2=a2[nt], v3=a3[nt], v4=a4[nt], v5=a5[nt];
    v1 += __shfl_xor(v1,16,64); v1 += __shfl_xor(v1,32,64);
    v2 += __shfl_xor(v2,16,64); v2 += __shfl_xor(v2,32,64);
    v3 += __shfl_xor(v3,16,64); v3 += __shfl_xor(v3,32,64);
    v4 += __shfl_xor(v4,16,64); v4 += __shfl_xor(v4,32,64);
    v5 += __shfl_xor(v5,16,64); v5 += __shfl_xor(v5,32,64);
    if (quad == 0) {
      int ch = nt*16 + col;
      lds_add(&red[ch], v1);
      lds_add(&red[64+ch], v2);
      lds_add(&red[128+ch], v3);
      lds_add(&red[192+ch], v4);
      lds_add(&red[256+ch], v5);
    }
  }
  __syncthreads();
  for (int i = threadIdx.x; i < 320; i += 256)
    A_p[(size_t)blockIdx.x*320 + i] = red[i];
}

// ---------------- KD v11: rolled 4-site loop + BOUNDED in-block kS fold ----------------
// 1024 blocks x 256 thr -> 4096 waves x 4 sites (ROLLED site loop; unrolling
// triggers the R13/R14 gather-hoist spill).
// Preamble: stage W2 in LDS; fold A_p[128][320] with #pragma unroll 8 (8
// in-flight loads, bounded pressure — R21's default unroll hit 128 VGPR) and
// momP[256][16] via mr-style 2-stage; compute sc1L/sh1L/W1sL in LDS.
// stats2 -> per-block partial store (no global atomics).
__global__ __launch_bounds__(256, 2) void kD_mfma(
    const float* __restrict__ pos, const int* __restrict__ idx,
    const float* __restrict__ g, const float* __restrict__ A_p,
    const float* __restrict__ momP, const float* __restrict__ W1,
    const float* __restrict__ gamma1, const float* __restrict__ beta1,
    const float* __restrict__ W2,
    float* __restrict__ stats2P, float* __restrict__ out_nf)
{
  __shared__ __bf16 W2T[CC2*72];   // 18 KB, [n][k] padded to 72
  __shared__ float red2[256];
  __shared__ float mr[256];
  __shared__ alignas(16) float AL[320];
  __shared__ float momL[16];
  __shared__ alignas(16) float sc1L[64];
  __shared__ alignas(16) float sh1L[64];
  __shared__ alignas(16) float W1sL[192];
  red2[threadIdx.x] = 0.f;
  // packed W2 transpose fill: thread t -> column n = t&127, k-half = t>>7.
  {
    const int n  = threadIdx.x & 127;
    const int k0 = (threadIdx.x >> 7) << 5;
    #pragma unroll
    for (int jj = 0; jj < 4; ++jj) {
      unsigned int pk[4];
      #pragma unroll
      for (int q2 = 0; q2 < 4; ++q2) {
        const int k = k0 + jj*8 + q2*2;
        __bf16 lo = (__bf16)W2[(size_t)k*CC2 + n];
        __bf16 hi = (__bf16)W2[(size_t)(k+1)*CC2 + n];
        unsigned short ulo, uhi;
        __builtin_memcpy(&ulo, &lo, 2);
        __builtin_memcpy(&uhi, &hi, 2);
        pk[q2] = ((unsigned int)uhi << 16) | (unsigned int)ulo;
      }
      __builtin_memcpy(&W2T[n*72 + k0 + jj*8], pk, 16);
    }
  }
  // BOUNDED kS fold (L2-hot, identical per block):
  for (int c = threadIdx.x; c < 320; c += 256) {
    float s = 0.f;
    #pragma unroll 8
    for (int blk = 0; blk < 128; ++blk) s += A_p[(size_t)blk*320 + c];
    AL[c] = s;
  }
  {
    const int i = threadIdx.x & 15, jq = threadIdx.x >> 4;
    float s = 0.f;
    #pragma unroll
    for (int q = 0; q < 16; ++q) s += momP[(size_t)(jq*16 + q)*16 + i];
    mr[threadIdx.x] = s;
  }
  __syncthreads();
  if (threadIdx.x < 16) {
    float tot = 0.f;
    #pragma unroll
    for (int q = 0; q < 16; ++q) tot += mr[q*16 + threadIdx.x];
    momL[threadIdx.x] = tot;
  }
  __syncthreads();
  if (threadIdx.x < CC1) {
    const int c = threadIdx.x;
    float wx = W1[c], wy = W1[CC1+c], wz = W1[2*CC1+c];
    float A1 = AL[c], A2 = AL[64+c];
    float A3x = AL[128+c], A3y = AL[192+c], A3z = AL[256+c];
    float sum1 = A1 + wx*momL[0] + wy*momL[1] + wz*momL[2];
    float ss = A2 + 2.f*(wx*A3x + wy*A3y + wz*A3z)
             + wx*wx*momL[3] + wy*wy*momL[4] + wz*wz*momL[5]
             + 2.f*(wx*wy*momL[6] + wx*wz*momL[7] + wy*wz*momL[8]);
    const float invN = 1.0f / (float)TOTROWS;
    float mean = sum1 * invN;
    float var  = ss * invN - mean*mean;
    float sc = rsqrtf(var + 1e-5f) * gamma1[c];
    float sh = beta1[c] - mean * sc;
    sc1L[c] = sc; sh1L[c] = sh;
    W1sL[c] = wx*sc; W1sL[64+c] = wy*sc; W1sL[128+c] = wz*sc;
  }
  __syncthreads();

  const int lane = threadIdx.x & 63;
  const int quad = lane >> 4;
  const int col  = lane & 15;
  const int wv = (blockIdx.x*256 + threadIdx.x) >> 6;  // 0..4095

  float ssum[8], ssq[8];
  #pragma unroll
  for (int nt = 0; nt < 8; ++nt) { ssum[nt] = 0.f; ssq[nt] = 0.f; }

  #pragma clang loop unroll(disable)
  for (int si = 0; si < 4; ++si) {
    const int site = wv*4 + si;
    const int b  = site >> 11;
    const int ls = site & (NN-1);
    const float* pb = pos + (size_t)b*NN*3;
    const int* ip = idx + (size_t)site*KK;

    const int ma = ip[col], mb = ip[16 + col];
    const float ccx = pb[ls*3], ccy = pb[ls*3+1], ccz = pb[ls*3+2];
    const float dxa = pb[ma*3]-ccx, dya = pb[ma*3+1]-ccy, dza = pb[ma*3+2]-ccz;
    const float dxb = pb[mb*3]-ccx, dyb = pb[mb*3+1]-ccy, dzb = pb[mb*3+2]-ccz;

    const float* gbase = g + (size_t)b*NN*CC1;
    const float* ra = gbase + (size_t)ma*CC1 + quad*8;
    const float* rb = gbase + (size_t)mb*CC1 + quad*8;
    f32x4 gA0 = *(const f32x4*)ra,      gA1 = *(const f32x4*)(ra+4);
    f32x4 gA2 = *(const f32x4*)(ra+32), gA3 = *(const f32x4*)(ra+36);
    f32x4 gB0 = *(const f32x4*)rb,      gB1 = *(const f32x4*)(rb+4);
    f32x4 gB2 = *(const f32x4*)(rb+32), gB3 = *(const f32x4*)(rb+36);

    // build A fragments: channel c = kt*32 + quad*8 + j (meta from LDS)
    bf16x8 A00, A01, A10, A11;   // A<mt><kt>
    {
      const int c0 = quad*8;
      f32x4 x0 = *(const f32x4*)&W1sL[c0],     x1 = *(const f32x4*)&W1sL[c0+4];
      f32x4 y0 = *(const f32x4*)&W1sL[64+c0],  y1 = *(const f32x4*)&W1sL[64+c0+4];
      f32x4 z0 = *(const f32x4*)&W1sL[128+c0], z1 = *(const f32x4*)&W1sL[128+c0+4];
      f32x4 s0 = *(const f32x4*)&sc1L[c0],     s1 = *(const f32x4*)&sc1L[c0+4];
      f32x4 h0 = *(const f32x4*)&sh1L[c0],     h1 = *(const f32x4*)&sh1L[c0+4];
      #pragma unroll
      for (int j = 0; j < 8; ++j) {
        float wx = (j<4)?x0[j]:x1[j-4], wy = (j<4)?y0[j]:y1[j-4];
        float wz = (j<4)?z0[j]:z1[j-4], sc = (j<4)?s0[j]:s1[j-4];
        float sh = (j<4)?h0[j]:h1[j-4];
        float ga = (j<4)?gA0[j]:gA1[j-4], gb = (j<4)?gB0[j]:gB1[j-4];
        float ta = fmaf(dza, wz, fmaf(dya, wy, fmaf(dxa, wx, sh)));
        A00[j] = (__bf16)fmaxf(fmaf(ga, sc, ta), 0.f);
        float tb = fmaf(dzb, wz, fmaf(dyb, wy, fmaf(dxb, wx, sh)));
        A10[j] = (__bf16)fmaxf(fmaf(gb, sc, tb), 0.f);
      }
    }
    {
      const int c0 = 32 + quad*8;
      f32x4 x0 = *(const f32x4*)&W1sL[c0],     x1 = *(const f32x4*)&W1sL[c0+4];
      f32x4 y0 = *(const f32x4*)&W1sL[64+c0],  y1 = *(const f32x4*)&W1sL[64+c0+4];
      f32x4 z0 = *(const f32x4*)&W1sL[128+c0], z1 = *(const f32x4*)&W1sL[128+c0+4];
      f32x4 s0 = *(const f32x4*)&sc1L[c0],     s1 = *(const f32x4*)&sc1L[c0+4];
      f32x4 h0 = *(const f32x4*)&sh1L[c0],     h1 = *(const f32x4*)&sh1L[c0+4];
      #pragma unroll
      for (int j = 0; j < 8; ++j) {
        float wx = (j<4)?x0[j]:x1[j-4], wy = (j<4)?y0[j]:y1[j-4];
        float wz = (j<4)?z0[j]:z1[j-4], sc = (j<4)?s0[j]:s1[j-4];
        float sh = (j<4)?h0[j]:h1[j-4];
        float ga = (j<4)?gA2[j]:gA3[j-4], gb = (j<4)?gB2[j]:gB3[j-4];
        float ta = fmaf(dza, wz, fmaf(dya, wy, fmaf(dxa, wx, sh)));
        A01[j] = (__bf16)fmaxf(fmaf(ga, sc, ta), 0.f);
        float tb = fmaf(dzb, wz, fmaf(dyb, wy, fmaf(dxb, wx, sh)));
        A11[j] = (__bf16)fmaxf(fmaf(gb, sc, tb), 0.f);
      }
    }

    float* outp = out_nf + (size_t)site*CC2;
    #pragma unroll
    for (int nt = 0; nt < 8; ++nt) {
      const bf16x8 B0 = *(const bf16x8*)&W2T[(nt*16 + col)*72 + quad*8];
      const bf16x8 B1 = *(const bf16x8*)&W2T[(nt*16 + col)*72 + 32 + quad*8];
      float mxv = -3.0e38f;
      f32x4 a = {0.f, 0.f, 0.f, 0.f};
      a = __builtin_amdgcn_mfma_f32_16x16x32_bf16(A00, B0, a, 0, 0, 0);
      a = __builtin_amdgcn_mfma_f32_16x16x32_bf16(A01, B1, a, 0, 0, 0);
      #pragma unroll
      for (int r = 0; r < 4; ++r) {
        float v = a[r];
        ssum[nt] += v; ssq[nt] = fmaf(v, v, ssq[nt]); mxv = fmaxf(mxv, v);
      }
      f32x4 a2 = {0.f, 0.f, 0.f, 0.f};
      a2 = __builtin_amdgcn_mfma_f32_16x16x32_bf16(A10, B0, a2, 0, 0, 0);
      a2 = __builtin_amdgcn_mfma_f32_16x16x32_bf16(A11, B1, a2, 0, 0, 0);
      #pragma unroll
      for (int r = 0; r < 4; ++r) {
        float v = a2[r];
        ssum[nt] += v; ssq[nt] = fmaf(v, v, ssq[nt]); mxv = fmaxf(mxv, v);
      }
      mxv = fmaxf(mxv, __shfl_xor(mxv, 16, 64));
      mxv = fmaxf(mxv, __shfl_xor(mxv, 32, 64));
      if ((nt & 3) == quad) outp[nt*16 + col] = mxv;   // pre-BN pooled
    }
  }

  #pragma unroll
  for (int nt = 0; nt < 8; ++nt) {
    float s = ssum[nt];
    s += __shfl_xor(s, 16, 64); s += __shfl_xor(s, 32, 64);
    float q = ssq[nt];
    q += __shfl_xor(q, 16, 64); q += __shfl_xor(q, 32, 64);
    if (lane < 16) {
      atomicAdd(&red2[nt*16 + col], s);
      atomicAdd(&red2[128 + nt*16 + col], q);
    }
  }
  __syncthreads();
  stats2P[(size_t)blockIdx.x*256 + threadIdx.x] = red2[threadIdx.x];
}

// ---------------- KR2: stats2P[1024][256] -> stats2[256] (narrow columns) ----------------
// 256 blocks x 256 thr; block c sums column c: 4 KB/block, 1 MB total.
__global__ __launch_bounds__(256) void kR2_stats(
    const float* __restrict__ stats2P, float* __restrict__ stats2)
{
  __shared__ float r[256];
  const int c = blockIdx.x;
  float s = 0.f;
  for (int i = threadIdx.x; i < DBLOCKS; i += 256)
    s += stats2P[(size_t)i*256 + c];
  r[threadIdx.x] = s;
  __syncthreads();
  for (int off = 128; off > 0; off >>= 1) {
    if (threadIdx.x < off) r[threadIdx.x] += r[threadIdx.x + off];
    __syncthreads();
  }
  if (threadIdx.x == 0) stats2[c] = r[0];
}

// ---------------- K45: position copy + bn2/relu in place ----------------
// blocks [0,192): copy position (49152 elems); blocks [192,8384): bn2.
__global__ __launch_bounds__(256) void k45_epi(const float* __restrict__ pos,
                                               const float* __restrict__ g2,
                                               const float* __restrict__ be2,
                                               const float* __restrict__ stats2,
                                               float* __restrict__ out)
{
  int i = blockIdx.x*256 + threadIdx.x;
  if (blockIdx.x < 192) { out[i] = pos[i]; return; }
  int j = i - 192*256;
  int c = j & (CC2-1);
  const float invc = 1.0f / (float)TOTROWS;
  float mean = stats2[c] * invc;
  float var  = stats2[128 + c] * invc - mean*mean;
  float sc = rsqrtf(var + 1e-5f) * g2[c];
  float sh = be2[c] - mean * sc;
  float* out_nf = out + (size_t)BB*NN*3;
  float x = out_nf[j];
  out_nf[j] = fmaxf(fmaf(x, sc, sh), 0.f);
}

extern "C" void kernel_launch(void* const* d_in, const int* in_sizes, int n_in,
                              void* d_out, int out_size, void* d_ws, size_t ws_size,
                              hipStream_t stream) {
  const float* pos  = (const float*)d_in[0];
  const float* feat = (const float*)d_in[1];
  const float* W1   = (const float*)d_in[2];
  const float* g1   = (const float*)d_in[3];
  const float* be1  = (const float*)d_in[4];
  const float* W2   = (const float*)d_in[5];
  const float* g2   = (const float*)d_in[6];
  const float* be2  = (const float*)d_in[7];
  float* out = (float*)d_out;
  float* out_nf = out + (size_t)BB*NN*3;

  char* w = (char*)d_ws;
  int*   idx    = (int*)w;                       // 2 MB @ 0
  float* stats2 = (float*)(w + 0x200000);        // 256
  float* A_p    = (float*)(w + 0x210000);        // 128*320 f32 = 160 KB
  float* momP   = (float*)(w + 0x250000);        // 256*16 f32 = 16 KB
  // Partials: 256 sets x 2048 f32 = 2 MB each, 8 MB @ 0x260000.
  // Live kQ -> kB (and kD's fold reads A_p/momP, not the partials).
  // stats2P (kD->kR2, 1 MB) overlays Py (dead after kB; kD runs after the
  // kB launch boundary). g fresh @ 0xA60000.
  float* Pc     = (float*)(w + 0x260000);
  float* Px     = Pc + (size_t)PSLICES*NN;
  float* Py     = Px + (size_t)PSLICES*NN;
  float* Pz     = Py + (size_t)PSLICES*NN;       // ends 0xA60000
  float* stats2P= (float*)(w + 0x660000);        // 1024*256 f32 = 1 MB (Py)
  float* g      = (float*)(w + 0xA60000);        // 4 MB fresh; ends 0xE60000

  kQ_ball_scatter<<<256, 1024, 0, stream>>>(pos, idx, Pc, Px, Py, Pz, momP);
  kB_g      <<<128, 256, 0, stream>>>(feat, W1, Pc, Px, Py, Pz, g, A_p);
  kD_mfma   <<<DBLOCKS, 256, 0, stream>>>(pos, idx, g, A_p, momP,
                                          W1, g1, be1, W2, stats2P, out_nf);
  kR2_stats <<<256, 256, 0, stream>>>(stats2P, stats2);
  k45_epi   <<<192 + (SITES*CC2)/256, 256, 0, stream>>>(pos, g2, be2, stats2, out);
}

// Round 14
// 172.935 us; speedup vs baseline: 1.0392x; 1.0392x over previous
//
#include <hip/hip_runtime.h>
#include <hip/hip_bf16.h>

// LocalAggregation: B=8, N=2048, K=32, D=64, C1=64, C2=128, R=0.15, EPS=1e-5
// Factored stats1 (validated R7-R10):
//   h1[row,c] = g[m,c] + dx*wx[c]+dy*wy[c]+dz*wz[c],  g = feat @ W1[3:]
//   sum1[c]   = SUM_m cnt[m] g[m,c] + wx M1x + wy M1y + wz M1z
//   sumsq1[c] = SUM_m cnt g^2 + 2(wx A3x + wy A3y + wz A3z) + quadratic moments
// FINAL (R25 = R19 verbatim, 174.3us harness-verified). Session ledger:
//   R13/R14: multi-site kD unroll -> gather hoist -> scratch spill. Rolled
//     loop / single-site body prevents it.
//   R15/R16: same-address global atomics = #blocks x ~130cy chain -> partial
//     stores + narrow reduce kernels everywhere.
//   R17: cross-block fences = L2 writeback storm (non-coherent XCD L2s).
//   R18: fence-free fusion kQ=k1+kP (block-local dep), kR->kB (dep crosses
//     launch boundary). 187us.
//   R19 (174us, BEST): kD v9 rolled 4-site @1024 blocks (W2 staging
//     amortized 4x; VGPR 48, Occ 44%).
//   R20: coop mega-kernel -> 64-VGPR cap -> spill (371us).
//   R21/R24: kS fold grafted into kD (default & bounded unroll) -> VGPR 128,
//     Occ ~19% (203/180us). Any graft raising kD peak VGPR > ~64 costs more
//     than the boundary it saves.
//   R22: k45 folding FULL stats2P per block = 256MB L3 traffic (195us).
//     RULE: redundant-fold cost = nblocks x fold_bytes << one boundary.
//   R23: kQ @2 blocks/CU neutral — kQ is not occupancy-bound.
//   Floor structure: ~90-95us kernels + ~60-80us across 6 launch boundaries;
//   all fusion classes measured-exhausted.
// gamma2>0 => max-pool commutes with bn2+relu (k45).

#define BB 8
#define NN 2048
#define KK 32
#define DD 64
#define CC1 64
#define CC2 128
#define TOTROWS (BB*NN*KK) // 524288
#define SITES (BB*NN)      // 16384
#define PSLICES 256        // partial sets (kQ blocks)
#define DBLOCKS 1024       // kD blocks

typedef __bf16 bf16x8 __attribute__((ext_vector_type(8)));
typedef float  f32x4  __attribute__((ext_vector_type(4)));

__device__ __forceinline__ void lds_add(float* p, float v) {
  __hip_atomic_fetch_add(p, v, __ATOMIC_RELAXED, __HIP_MEMORY_SCOPE_WORKGROUP);
}

// ---------------- KQ: fused ball query + scatter (k1+kP, block-local dep) ----------------
// 256 blocks x 1024 thr; block = (batch, 64-site slice).
// Phase 1: stage P[2048] float4 (32 KB) + zero accumulators.
// Phase 2: ball query, 16 waves x 4 queries; idx -> global AND idxL (LDS).
// Phase 3: scatter from idxL, positions from LDS P. u32 2^22 fixed point:
//   per-block |sum dx| <= 2048 * 0.15 * 2^22 = 1.29e9 < 2^31.
// Phase 4: partial stores Pc/Px/Py/Pz + momP. ZERO global atomics, no fences.
__global__ __launch_bounds__(1024, 1) void kQ_ball_scatter(
    const float* __restrict__ pos, int* __restrict__ idx,
    float* __restrict__ Pc, float* __restrict__ Px,
    float* __restrict__ Py, float* __restrict__ Pz,
    float* __restrict__ momP)
{
  __shared__ float4 P[NN];                               // 32 KB
  __shared__ unsigned int Sc[NN], Sx[NN], Sy[NN], Sz[NN]; // 32 KB
  __shared__ int idxL[64*KK];                            // 8 KB
  __shared__ float mred[16*9];
  const int b = blockIdx.x >> 5;       // 32 slices per batch
  const int slice = blockIdx.x & 31;   // 64 sites each
  // phase 1: stage P (verbatim k1 arithmetic: no contraction) + zero acc
  for (int i = threadIdx.x; i < NN; i += 1024) {
    const float* p = pos + ((size_t)b*NN + i)*3;
    float x = p[0], y = p[1], z = p[2];
    float s = __fadd_rn(__fadd_rn(__fmul_rn(x,x), __fmul_rn(y,y)), __fmul_rn(z,z));
    P[i] = make_float4(x, y, z, s);
    Sc[i] = 0u; Sx[i] = 0u; Sy[i] = 0u; Sz[i] = 0u;
  }
  __syncthreads();
  // phase 2: ball query (16 waves, 4 site-local queries each)
  const int wave = threadIdx.x >> 6, lane = threadIdx.x & 63;
  const float R2 = (float)(0.15 * 0.15);
  const unsigned long long lt = (lane == 63) ? 0x7fffffffffffffffull
                                             : ((1ull << lane) - 1ull);
  for (int qi = wave; qi < 64; qi += 16) {
    const int q = slice*64 + qi;             // batch-local point id
    const float4 Q = P[q];
    int* ip = idx + ((size_t)b*NN + q)*KK;
    int* il = idxL + qi*KK;
    int cnt = 0, first = -1;
    for (int step = 0; step < 32; ++step) {
      float4 p = P[step*64 + lane];
      float d = __fmul_rn(Q.x, p.x);
      d = fmaf(Q.y, p.y, d);
      d = fmaf(Q.z, p.z, d);
      float sq = __fsub_rn(__fadd_rn(Q.w, p.w), __fmul_rn(2.0f, d));
      bool in = !(sq > R2);
      unsigned long long mask = __ballot(in);
      if (first < 0 && mask) first = step*64 + (int)__builtin_ctzll(mask);
      int dst = cnt + (int)__popcll(mask & lt);
      if (in && dst < KK) { ip[dst] = step*64 + lane; il[dst] = step*64 + lane; }
      cnt += (int)__popcll(mask);
      if (cnt >= KK) break;
    }
    if (lane >= cnt && lane < KK) { ip[lane] = first; il[lane] = first; }
  }
  __syncthreads();
  // phase 3: scatter (thread = (site sl, k-group kg of 2 k's))
  const int sl = threadIdx.x >> 4;     // site-local 0..63
  const int kg = threadIdx.x & 15;
  const int ip0 = idxL[sl*KK];
  const float4 C = P[slice*64 + sl];
  const float FS = 4194304.0f;         // 2^22
  float m1x=0.f,m1y=0.f,m1z=0.f,mxx=0.f,myy=0.f,mzz=0.f,mxy=0.f,mxz=0.f,myz=0.f;
  int wt = 0;
  #pragma unroll
  for (int j = 0; j < 2; ++j) {
    const int k = kg*2 + j;
    const int m = idxL[sl*KK + k];
    const float4 Pm = P[m];
    float dx = Pm.x - C.x;
    float dy = Pm.y - C.y;
    float dz = Pm.z - C.z;
    if (k > 0 && m == ip0) {
      ++wt;                             // padding: aggregate
    } else {
      atomicAdd(&Sc[m], 1u);            // ds_add_u32
      atomicAdd(&Sx[m], (unsigned int)__float2int_rn(dx*FS));
      atomicAdd(&Sy[m], (unsigned int)__float2int_rn(dy*FS));
      atomicAdd(&Sz[m], (unsigned int)__float2int_rn(dz*FS));
    }
    m1x += dx; m1y += dy; m1z += dz;    // moments include padding rows
    mxx = fmaf(dx,dx,mxx); myy = fmaf(dy,dy,myy); mzz = fmaf(dz,dz,mzz);
    mxy = fmaf(dx,dy,mxy); mxz = fmaf(dx,dz,mxz); myz = fmaf(dy,dz,myz);
  }
  if (wt > 0) {
    const float4 P0 = P[ip0];
    float dx0 = P0.x - C.x;
    float dy0 = P0.y - C.y;
    float dz0 = P0.z - C.z;
    atomicAdd(&Sc[ip0], (unsigned int)wt);
    atomicAdd(&Sx[ip0], (unsigned int)(wt*__float2int_rn(dx0*FS)));
    atomicAdd(&Sy[ip0], (unsigned int)(wt*__float2int_rn(dy0*FS)));
    atomicAdd(&Sz[ip0], (unsigned int)(wt*__float2int_rn(dz0*FS)));
  }
  // per-wave moment reduce -> LDS -> per-block partial store
  const int wv = threadIdx.x >> 6;     // 0..15
  float vals[9] = {m1x,m1y,m1z,mxx,myy,mzz,mxy,mxz,myz};
  #pragma unroll
  for (int i = 0; i < 9; ++i) {
    float v = vals[i];
    #pragma unroll
    for (int s = 1; s < 64; s <<= 1) v += __shfl_xor(v, s, 64);
    if (lane == 0) mred[wv*9 + i] = v;
  }
  __syncthreads();
  // phase 4: partial stores
  const float IS = 2.38418579101562500e-7f;  // 2^-22
  float* pc = Pc + (size_t)blockIdx.x*NN;
  float* px = Px + (size_t)blockIdx.x*NN;
  float* py = Py + (size_t)blockIdx.x*NN;
  float* pz = Pz + (size_t)blockIdx.x*NN;
  for (int i = threadIdx.x; i < NN; i += 1024) {
    pc[i] = (float)Sc[i];
    px[i] = (float)(int)Sx[i] * IS;
    py[i] = (float)(int)Sy[i] * IS;
    pz[i] = (float)(int)Sz[i] * IS;
  }
  if (threadIdx.x < 9) {
    float s = 0.f;
    #pragma unroll
    for (int w2 = 0; w2 < 16; ++w2) s += mred[w2*9 + threadIdx.x];
    momP[(size_t)blockIdx.x*16 + threadIdx.x] = s;
  }
}

// ---------------- KB v4: g = feat @ W1[3:] + A-sums; kR fused cooperatively ----------------
// 128 blocks x 256 thr -> 512 waves x 2 M-tiles; block covers 128 rows (one batch).
// Staging: cntL/dxL/dyL/dzL[128] = 32-partial sums for this block's rows
// (dep crosses the kQ->kB launch boundary; no fences).
// A layout: [0:64) Sum cnt*g, [64:128) Sum cnt*g^2, [128:192) Sum g*DX,
//           [192:256) Sum g*DY, [256:320) Sum g*DZ  -> A_p[blk][320].
__global__ __launch_bounds__(256) void kB_g(const float* __restrict__ feat,
                                            const float* __restrict__ W1,
                                            const float* __restrict__ Pc,
                                            const float* __restrict__ Px,
                                            const float* __restrict__ Py,
                                            const float* __restrict__ Pz,
                                            float* __restrict__ g,
                                            float* __restrict__ A_p)
{
  __shared__ float red[320];
  __shared__ float cntL[128], dxL[128], dyL[128], dzL[128];
  for (int i = threadIdx.x; i < 320; i += 256) red[i] = 0.f;
  const int row0B = blockIdx.x * 128;
  const int bb = row0B >> 11;          // batch of this block (128 | 2048)
  for (int r2 = threadIdx.x; r2 < 128; r2 += 256) {
    const int m = (row0B + r2) & (NN-1);
    float s0 = 0.f, s1 = 0.f, s2 = 0.f, s3 = 0.f;
    #pragma unroll 4
    for (int q = 0; q < 32; ++q) {
      const size_t base = (size_t)(bb*32 + q)*NN + m;
      s0 += Pc[base]; s1 += Px[base]; s2 += Py[base]; s3 += Pz[base];
    }
    cntL[r2] = s0; dxL[r2] = s1; dyL[r2] = s2; dzL[r2] = s3;
  }
  __syncthreads();
  const int lane = threadIdx.x & 63;
  const int quad = lane >> 4;
  const int col  = lane & 15;
  const int gw = (blockIdx.x*256 + threadIdx.x) >> 6;   // 0..511

  bf16x8 Bf[2][4];
  #pragma unroll
  for (int kt = 0; kt < 2; ++kt)
    #pragma unroll
    for (int nt = 0; nt < 4; ++nt) {
      bf16x8 v;
      #pragma unroll
      for (int j = 0; j < 8; ++j)
        v[j] = (__bf16)W1[(3 + kt*32 + quad*8 + j)*CC1 + nt*16 + col];
      Bf[kt][nt] = v;
    }
  float a1[4], a2[4], a3[4], a4[4], a5[4];
  #pragma unroll
  for (int nt = 0; nt < 4; ++nt) { a1[nt]=0.f; a2[nt]=0.f; a3[nt]=0.f; a4[nt]=0.f; a5[nt]=0.f; }

  for (int t = 0; t < 2; ++t) {
    const int row0 = (gw*2 + t) * 16;
    bf16x8 Af[2];
    #pragma unroll
    for (int kt = 0; kt < 2; ++kt) {
      const float4* fp =
        (const float4*)(feat + (size_t)(row0 + col)*DD + kt*32 + quad*8);
      float4 f0 = fp[0], f1 = fp[1];
      float fv[8] = {f0.x,f0.y,f0.z,f0.w,f1.x,f1.y,f1.z,f1.w};
      bf16x8 v;
      #pragma unroll
      for (int j = 0; j < 8; ++j) v[j] = (__bf16)fv[j];
      Af[kt] = v;
    }
    float cw[4], dxw[4], dyw[4], dzw[4];
    #pragma unroll
    for (int r = 0; r < 4; ++r) {
      int rl = row0 - row0B + quad*4 + r;   // 0..127 within block
      cw[r] = cntL[rl]; dxw[r] = dxL[rl]; dyw[r] = dyL[rl]; dzw[r] = dzL[rl];
    }
    #pragma unroll
    for (int nt = 0; nt < 4; ++nt) {
      f32x4 a = {0.f, 0.f, 0.f, 0.f};
      a = __builtin_amdgcn_mfma_f32_16x16x32_bf16(Af[0], Bf[0][nt], a, 0, 0, 0);
      a = __builtin_amdgcn_mfma_f32_16x16x32_bf16(Af[1], Bf[1][nt], a, 0, 0, 0);
      #pragma unroll
      for (int r = 0; r < 4; ++r) {
        float v = a[r];
        g[(size_t)(row0 + quad*4 + r)*CC1 + nt*16 + col] = v;
        float cv = cw[r]*v;
        a1[nt] += cv; a2[nt] = fmaf(cv, v, a2[nt]);
        a3[nt] = fmaf(dxw[r], v, a3[nt]);
        a4[nt] = fmaf(dyw[r], v, a4[nt]);
        a5[nt] = fmaf(dzw[r], v, a5[nt]);
      }
    }
  }
  #pragma unroll
  for (int nt = 0; nt < 4; ++nt) {
    float v1=a1[nt], v2=a2[nt], v3=a3[nt], v4=a4[nt], v5=a5[nt];
    v1 += __shfl_xor(v1,16,64); v1 += __shfl_xor(v1,32,64);
    v2 += __shfl_xor(v2,16,64); v2 += __shfl_xor(v2,32,64);
    v3 += __shfl_xor(v3,16,64); v3 += __shfl_xor(v3,32,64);
    v4 += __shfl_xor(v4,16,64); v4 += __shfl_xor(v4,32,64);
    v5 += __shfl_xor(v5,16,64); v5 += __shfl_xor(v5,32,64);
    if (quad == 0) {
      int ch = nt*16 + col;
      lds_add(&red[ch], v1);
      lds_add(&red[64+ch], v2);
      lds_add(&red[128+ch], v3);
      lds_add(&red[192+ch], v4);
      lds_add(&red[256+ch], v5);
    }
  }
  __syncthreads();
  for (int i = threadIdx.x; i < 320; i += 256)
    A_p[(size_t)blockIdx.x*320 + i] = red[i];
}

// ---------------- KS v2: reduce A_p + momP, assemble stats1 -> sc1, sh1, W1s ----------------
__global__ __launch_bounds__(256) void kS_fold(
    const float* __restrict__ W1, const float* __restrict__ gamma1,
    const float* __restrict__ beta1, const float* __restrict__ A_p,
    const float* __restrict__ momP,
    float* __restrict__ sc1, float* __restrict__ sh1, float* __restrict__ W1s)
{
  __shared__ float AL[320];
  __shared__ float mr[256];
  __shared__ float momL[16];
  // momP[256][16] -> momL
  {
    const int t = threadIdx.x;
    const int i = t & 15, jq = t >> 4;
    float s = 0.f;
    #pragma unroll
    for (int q = 0; q < 16; ++q) s += momP[(size_t)(jq*16 + q)*16 + i];
    mr[t] = s;
  }
  // A_p[128][320] -> AL
  for (int c = threadIdx.x; c < 320; c += 256) {
    float s = 0.f;
    for (int blk = 0; blk < 128; ++blk) s += A_p[(size_t)blk*320 + c];
    AL[c] = s;
  }
  __syncthreads();
  if (threadIdx.x < 16) {
    float tot = 0.f;
    #pragma unroll
    for (int q = 0; q < 16; ++q) tot += mr[q*16 + threadIdx.x];
    momL[threadIdx.x] = tot;
  }
  __syncthreads();
  const int c = threadIdx.x;
  if (c >= CC1) return;
  float wx = W1[c], wy = W1[CC1+c], wz = W1[2*CC1+c];
  float A1 = AL[c], A2 = AL[64+c];
  float A3x = AL[128+c], A3y = AL[192+c], A3z = AL[256+c];
  float sum1 = A1 + wx*momL[0] + wy*momL[1] + wz*momL[2];
  float ss = A2 + 2.f*(wx*A3x + wy*A3y + wz*A3z)
           + wx*wx*momL[3] + wy*wy*momL[4] + wz*wz*momL[5]
           + 2.f*(wx*wy*momL[6] + wx*wz*momL[7] + wy*wz*momL[8]);
  const float invN = 1.0f / (float)TOTROWS;
  float mean = sum1 * invN;
  float var  = ss * invN - mean*mean;
  float sc = rsqrtf(var + 1e-5f) * gamma1[c];
  float sh = beta1[c] - mean * sc;
  sc1[c] = sc; sh1[c] = sh;
  W1s[c] = wx*sc; W1s[64+c] = wy*sc; W1s[128+c] = wz*sc;
}

// ---------------- KD v9 (BEST): rolled 4-site loop, LDS W2, partial stores ----------------
// 1024 blocks x 256 thr -> 4096 waves x 4 sites (ROLLED loop, unroll-disabled:
// unrolling lets the scheduler hoist all sites' gathers -> spill, R13/R14).
// W2 staged once per block (staging/pack was ~1/3 of VALU at 4096 blocks).
// stats2 -> per-block partial store (no global atomics). VGPR 48, Occ 44%.
__global__ __launch_bounds__(256, 2) void kD_mfma(
    const float* __restrict__ pos, const int* __restrict__ idx,
    const float* __restrict__ g, const float* __restrict__ sc1,
    const float* __restrict__ sh1, const float* __restrict__ W1s,
    const float* __restrict__ W2,
    float* __restrict__ stats2P, float* __restrict__ out_nf)
{
  __shared__ __bf16 W2T[CC2*72];   // 18 KB, [n][k] padded to 72
  __shared__ float red2[256];
  red2[threadIdx.x] = 0.f;
  // packed transpose fill: thread t -> column n = t&127, k-half = t>>7.
  {
    const int n  = threadIdx.x & 127;
    const int k0 = (threadIdx.x >> 7) << 5;
    #pragma unroll
    for (int jj = 0; jj < 4; ++jj) {
      unsigned int pk[4];
      #pragma unroll
      for (int q2 = 0; q2 < 4; ++q2) {
        const int k = k0 + jj*8 + q2*2;
        __bf16 lo = (__bf16)W2[(size_t)k*CC2 + n];
        __bf16 hi = (__bf16)W2[(size_t)(k+1)*CC2 + n];
        unsigned short ulo, uhi;
        __builtin_memcpy(&ulo, &lo, 2);
        __builtin_memcpy(&uhi, &hi, 2);
        pk[q2] = ((unsigned int)uhi << 16) | (unsigned int)ulo;
      }
      __builtin_memcpy(&W2T[n*72 + k0 + jj*8], pk, 16);
    }
  }
  __syncthreads();

  const int lane = threadIdx.x & 63;
  const int quad = lane >> 4;
  const int col  = lane & 15;
  const int wv = (blockIdx.x*256 + threadIdx.x) >> 6;  // 0..4095

  float ssum[8], ssq[8];
  #pragma unroll
  for (int nt = 0; nt < 8; ++nt) { ssum[nt] = 0.f; ssq[nt] = 0.f; }

  #pragma clang loop unroll(disable)
  for (int si = 0; si < 4; ++si) {
    const int site = wv*4 + si;
    const int b  = site >> 11;
    const int ls = site & (NN-1);
    const float* pb = pos + (size_t)b*NN*3;
    const int* ip = idx + (size_t)site*KK;

    const int ma = ip[col], mb = ip[16 + col];
    const float ccx = pb[ls*3], ccy = pb[ls*3+1], ccz = pb[ls*3+2];
    const float dxa = pb[ma*3]-ccx, dya = pb[ma*3+1]-ccy, dza = pb[ma*3+2]-ccz;
    const float dxb = pb[mb*3]-ccx, dyb = pb[mb*3+1]-ccy, dzb = pb[mb*3+2]-ccz;

    const float* gbase = g + (size_t)b*NN*CC1;
    const float* ra = gbase + (size_t)ma*CC1 + quad*8;
    const float* rb = gbase + (size_t)mb*CC1 + quad*8;
    f32x4 gA0 = *(const f32x4*)ra,      gA1 = *(const f32x4*)(ra+4);
    f32x4 gA2 = *(const f32x4*)(ra+32), gA3 = *(const f32x4*)(ra+36);
    f32x4 gB0 = *(const f32x4*)rb,      gB1 = *(const f32x4*)(rb+4);
    f32x4 gB2 = *(const f32x4*)(rb+32), gB3 = *(const f32x4*)(rb+36);

    // build A fragments: channel c = kt*32 + quad*8 + j
    bf16x8 A00, A01, A10, A11;   // A<mt><kt>
    {
      const int c0 = quad*8;
      f32x4 x0 = *(const f32x4*)&W1s[c0],     x1 = *(const f32x4*)&W1s[c0+4];
      f32x4 y0 = *(const f32x4*)&W1s[64+c0],  y1 = *(const f32x4*)&W1s[64+c0+4];
      f32x4 z0 = *(const f32x4*)&W1s[128+c0], z1 = *(const f32x4*)&W1s[128+c0+4];
      f32x4 s0 = *(const f32x4*)&sc1[c0],     s1 = *(const f32x4*)&sc1[c0+4];
      f32x4 h0 = *(const f32x4*)&sh1[c0],     h1 = *(const f32x4*)&sh1[c0+4];
      #pragma unroll
      for (int j = 0; j < 8; ++j) {
        float wx = (j<4)?x0[j]:x1[j-4], wy = (j<4)?y0[j]:y1[j-4];
        float wz = (j<4)?z0[j]:z1[j-4], sc = (j<4)?s0[j]:s1[j-4];
        float sh = (j<4)?h0[j]:h1[j-4];
        float ga = (j<4)?gA0[j]:gA1[j-4], gb = (j<4)?gB0[j]:gB1[j-4];
        float ta = fmaf(dza, wz, fmaf(dya, wy, fmaf(dxa, wx, sh)));
        A00[j] = (__bf16)fmaxf(fmaf(ga, sc, ta), 0.f);
        float tb = fmaf(dzb, wz, fmaf(dyb, wy, fmaf(dxb, wx, sh)));
        A10[j] = (__bf16)fmaxf(fmaf(gb, sc, tb), 0.f);
      }
    }
    {
      const int c0 = 32 + quad*8;
      f32x4 x0 = *(const f32x4*)&W1s[c0],     x1 = *(const f32x4*)&W1s[c0+4];
      f32x4 y0 = *(const f32x4*)&W1s[64+c0],  y1 = *(const f32x4*)&W1s[64+c0+4];
      f32x4 z0 = *(const f32x4*)&W1s[128+c0], z1 = *(const f32x4*)&W1s[128+c0+4];
      f32x4 s0 = *(const f32x4*)&sc1[c0],     s1 = *(const f32x4*)&sc1[c0+4];
      f32x4 h0 = *(const f32x4*)&sh1[c0],     h1 = *(const f32x4*)&sh1[c0+4];
      #pragma unroll
      for (int j = 0; j < 8; ++j) {
        float wx = (j<4)?x0[j]:x1[j-4], wy = (j<4)?y0[j]:y1[j-4];
        float wz = (j<4)?z0[j]:z1[j-4], sc = (j<4)?s0[j]:s1[j-4];
        float sh = (j<4)?h0[j]:h1[j-4];
        float ga = (j<4)?gA2[j]:gA3[j-4], gb = (j<4)?gB2[j]:gB3[j-4];
        float ta = fmaf(dza, wz, fmaf(dya, wy, fmaf(dxa, wx, sh)));
        A01[j] = (__bf16)fmaxf(fmaf(ga, sc, ta), 0.f);
        float tb = fmaf(dzb, wz, fmaf(dyb, wy, fmaf(dxb, wx, sh)));
        A11[j] = (__bf16)fmaxf(fmaf(gb, sc, tb), 0.f);
      }
    }

    float* outp = out_nf + (size_t)site*CC2;
    #pragma unroll
    for (int nt = 0; nt < 8; ++nt) {
      const bf16x8 B0 = *(const bf16x8*)&W2T[(nt*16 + col)*72 + quad*8];
      const bf16x8 B1 = *(const bf16x8*)&W2T[(nt*16 + col)*72 + 32 + quad*8];
      float mxv = -3.0e38f;
      f32x4 a = {0.f, 0.f, 0.f, 0.f};
      a = __builtin_amdgcn_mfma_f32_16x16x32_bf16(A00, B0, a, 0, 0, 0);
      a = __builtin_amdgcn_mfma_f32_16x16x32_bf16(A01, B1, a, 0, 0, 0);
      #pragma unroll
      for (int r = 0; r < 4; ++r) {
        float v = a[r];
        ssum[nt] += v; ssq[nt] = fmaf(v, v, ssq[nt]); mxv = fmaxf(mxv, v);
      }
      f32x4 a2 = {0.f, 0.f, 0.f, 0.f};
      a2 = __builtin_amdgcn_mfma_f32_16x16x32_bf16(A10, B0, a2, 0, 0, 0);
      a2 = __builtin_amdgcn_mfma_f32_16x16x32_bf16(A11, B1, a2, 0, 0, 0);
      #pragma unroll
      for (int r = 0; r < 4; ++r) {
        float v = a2[r];
        ssum[nt] += v; ssq[nt] = fmaf(v, v, ssq[nt]); mxv = fmaxf(mxv, v);
      }
      mxv = fmaxf(mxv, __shfl_xor(mxv, 16, 64));
      mxv = fmaxf(mxv, __shfl_xor(mxv, 32, 64));
      if ((nt & 3) == quad) outp[nt*16 + col] = mxv;   // pre-BN pooled
    }
  }

  #pragma unroll
  for (int nt = 0; nt < 8; ++nt) {
    float s = ssum[nt];
    s += __shfl_xor(s, 16, 64); s += __shfl_xor(s, 32, 64);
    float q = ssq[nt];
    q += __shfl_xor(q, 16, 64); q += __shfl_xor(q, 32, 64);
    if (lane < 16) {
      atomicAdd(&red2[nt*16 + col], s);
      atomicAdd(&red2[128 + nt*16 + col], q);
    }
  }
  __syncthreads();
  stats2P[(size_t)blockIdx.x*256 + threadIdx.x] = red2[threadIdx.x];
}

// ---------------- KR2: stats2P[1024][256] -> stats2[256] ----------------
// 256 blocks x 256 thr; block c sums column c (4 KB/block, 1 MB total).
__global__ __launch_bounds__(256) void kR2_stats(
    const float* __restrict__ stats2P, float* __restrict__ stats2)
{
  __shared__ float r[256];
  const int c = blockIdx.x;
  float s = 0.f;
  for (int i = threadIdx.x; i < DBLOCKS; i += 256)
    s += stats2P[(size_t)i*256 + c];
  r[threadIdx.x] = s;
  __syncthreads();
  for (int off = 128; off > 0; off >>= 1) {
    if (threadIdx.x < off) r[threadIdx.x] += r[threadIdx.x + off];
    __syncthreads();
  }
  if (threadIdx.x == 0) stats2[c] = r[0];
}

// ---------------- K45: position copy + bn2/relu in place ----------------
// blocks [0,192): copy position (49152 elems); blocks [192,8384): bn2.
__global__ __launch_bounds__(256) void k45_epi(const float* __restrict__ pos,
                                               const float* __restrict__ g2,
                                               const float* __restrict__ be2,
                                               const float* __restrict__ stats2,
                                               float* __restrict__ out)
{
  int i = blockIdx.x*256 + threadIdx.x;
  if (blockIdx.x < 192) { out[i] = pos[i]; return; }
  int j = i - 192*256;
  int c = j & (CC2-1);
  const float invc = 1.0f / (float)TOTROWS;
  float mean = stats2[c] * invc;
  float var  = stats2[128 + c] * invc - mean*mean;
  float sc = rsqrtf(var + 1e-5f) * g2[c];
  float sh = be2[c] - mean * sc;
  float* out_nf = out + (size_t)BB*NN*3;
  float x = out_nf[j];
  out_nf[j] = fmaxf(fmaf(x, sc, sh), 0.f);
}

extern "C" void kernel_launch(void* const* d_in, const int* in_sizes, int n_in,
                              void* d_out, int out_size, void* d_ws, size_t ws_size,
                              hipStream_t stream) {
  const float* pos  = (const float*)d_in[0];
  const float* feat = (const float*)d_in[1];
  const float* W1   = (const float*)d_in[2];
  const float* g1   = (const float*)d_in[3];
  const float* be1  = (const float*)d_in[4];
  const float* W2   = (const float*)d_in[5];
  const float* g2   = (const float*)d_in[6];
  const float* be2  = (const float*)d_in[7];
  float* out = (float*)d_out;
  float* out_nf = out + (size_t)BB*NN*3;

  char* w = (char*)d_ws;
  int*   idx    = (int*)w;                       // 2 MB @ 0
  float* stats2 = (float*)(w + 0x200000);        // 256
  float* sc1    = stats2 + 256;                  // 64
  float* sh1    = sc1 + 64;                      // 64
  float* W1s    = sh1 + 64;                      // 192
  float* A_p    = (float*)(w + 0x210000);        // 128*320 f32 = 160 KB
  float* momP   = (float*)(w + 0x250000);        // 256*16 f32 = 16 KB
  // Partials: 256 sets x 2048 f32 = 2 MB each, 8 MB @ 0x260000.
  // Live kQ -> kB. stats2P (kD->kR2, 1 MB) overlays Py (dead after kB;
  // kD runs after the kB launch boundary). g fresh @ 0xA60000.
  float* Pc     = (float*)(w + 0x260000);
  float* Px     = Pc + (size_t)PSLICES*NN;
  float* Py     = Px + (size_t)PSLICES*NN;
  float* Pz     = Py + (size_t)PSLICES*NN;       // ends 0xA60000
  float* stats2P= (float*)(w + 0x660000);        // 1024*256 f32 = 1 MB (Py)
  float* g      = (float*)(w + 0xA60000);        // 4 MB fresh; ends 0xE60000

  kQ_ball_scatter<<<256, 1024, 0, stream>>>(pos, idx, Pc, Px, Py, Pz, momP);
  kB_g      <<<128, 256, 0, stream>>>(feat, W1, Pc, Px, Py, Pz, g, A_p);
  kS_fold   <<<1, 256, 0, stream>>>(W1, g1, be1, A_p, momP, sc1, sh1, W1s);
  kD_mfma   <<<DBLOCKS, 256, 0, stream>>>(pos, idx, g, sc1, sh1, W1s, W2,
                                          stats2P, out_nf);
  kR2_stats <<<256, 256, 0, stream>>>(stats2P, stats2);
  k45_epi   <<<192 + (SITES*CC2)/256, 256, 0, stream>>>(pos, g2, be2, stats2, out);
}